// Round 10
// baseline (293.043 us; speedup 1.0000x reference)
//
#include <hip/hip_runtime.h>
#include <hip/hip_cooperative_groups.h>

namespace cg = cooperative_groups;

#define NTOK 4096
#define CH 64
#define LOG2E 1.4426950408889634f

typedef __bf16 bf8 __attribute__((ext_vector_type(8)));
typedef __bf16 bf4 __attribute__((ext_vector_type(4)));
typedef _Float16 h8 __attribute__((ext_vector_type(8)));
typedef _Float16 h4 __attribute__((ext_vector_type(4)));
typedef float f4 __attribute__((ext_vector_type(4)));

__device__ __forceinline__ f4 mfma16(bf8 a, bf8 b, f4 c) {
    return __builtin_amdgcn_mfma_f32_16x16x32_bf16(a, b, c, 0, 0, 0);
}
__device__ __forceinline__ f4 mfma16h(h4 a, h4 b, f4 c) {
    return __builtin_amdgcn_mfma_f32_16x16x16f16(a, b, c, 0, 0, 0);
}

// =================== fused single cooperative kernel (grid 512 x 256) ====================
// Phase A: GN partial sums (all blocks) + weight transpose (blocks 0..3)
// Phase B: GN + QKV projection (64 rows/block)
// Phase C: attention + output projection + bias + GN residual   (R9 body, unchanged)
__global__ __launch_bounds__(256) void fused_all(const float* __restrict__ x,
                                                 const float* __restrict__ gamma,
                                                 const float* __restrict__ beta,
                                                 const float* __restrict__ wq,
                                                 const float* __restrict__ bq,
                                                 const float* __restrict__ wk,
                                                 const float* __restrict__ bk,
                                                 const float* __restrict__ wv,
                                                 const float* __restrict__ bv,
                                                 const float* __restrict__ wp,
                                                 const float* __restrict__ bp,
                                                 __bf16* __restrict__ q,
                                                 __bf16* __restrict__ k,
                                                 _Float16* __restrict__ vT,
                                                 __bf16* __restrict__ wqt,
                                                 __bf16* __restrict__ wkt,
                                                 __bf16* __restrict__ wvt,
                                                 __bf16* __restrict__ wpt,
                                                 float* __restrict__ gpart,
                                                 float* __restrict__ out) {
    __shared__ __align__(16) char smem[46144];
    int t = threadIdx.x;
    int bid = blockIdx.x;

    // ---------------- Phase A ----------------
    {
        float* ls  = (float*)(smem + 16640);
        float* lss = (float*)(smem + 17664);
        int b = bid >> 6, slab = bid & 63;
        const float4* xb = (const float4*)(x + (size_t)(b * NTOK + slab * 64) * CH);
        float s = 0.f, ss = 0.f;
        for (int i = 0; i < 4; ++i) {
            int row = (t >> 4) + i * 16;
            float4 v = xb[row * 16 + (t & 15)];
            s  += v.x + v.y + v.z + v.w;
            ss += v.x * v.x + v.y * v.y + v.z * v.z + v.w * v.w;
        }
        ls[t] = s; lss[t] = ss;
        __syncthreads();
        if (t < 8) {
            float a = 0.f, aa = 0.f;
            for (int p = 0; p < 16; ++p) {
                a  += ls[p * 16 + 2 * t]  + ls[p * 16 + 2 * t + 1];
                aa += lss[p * 16 + 2 * t] + lss[p * 16 + 2 * t + 1];
            }
            gpart[((b * 64 + slab) * 8 + t) * 2 + 0] = a;
            gpart[((b * 64 + slab) * 8 + t) * 2 + 1] = aa;
        }
        if (bid < 4) {   // weight transpose + bf16 convert
            float (*ts)[65] = (float (*)[65])(smem);
            const float* src = (bid == 0) ? wq : (bid == 1) ? wk : (bid == 2) ? wv : wp;
            __bf16* dst      = (bid == 0) ? wqt : (bid == 1) ? wkt : (bid == 2) ? wvt : wpt;
            for (int i = 0; i < 16; ++i) {
                int e = i * 256 + t;
                ts[e >> 6][e & 63] = src[e];
            }
            __syncthreads();
            int o = t >> 2, seg = t & 3;
            for (int j = 0; j < 16; ++j) {
                int in = seg * 16 + j;
                dst[o * 64 + in] = (__bf16)ts[in][o];
            }
        }
    }

    cg::this_grid().sync();

    // ---------------- Phase B: GN + QKV (64 rows per block) ----------------
    {
        __bf16 (*W)[64][72] = (__bf16 (*)[64][72])(smem);
        __bf16 (*Hl)[72]    = (__bf16 (*)[72])(smem + 27648);
        _Float16 (*Vst)[68] = (_Float16 (*)[68])(smem + 36864);
        float* red   = (float*)(smem + 45568);
        float* sstat = (float*)(smem + 46080);
        size_t rowbase = (size_t)bid * 64;
        int b = (int)(rowbase >> 12), tokbase = (int)(rowbase & 4095);
        if (t < 64) {
            int gi = t & 7, c = t >> 3;
            const float2* gp = (const float2*)gpart + (size_t)b * 512 + gi;
            float a = 0.f, aa = 0.f;
            for (int p = c * 8; p < c * 8 + 8; ++p) {
                float2 v = gp[(size_t)p * 8];
                a += v.x; aa += v.y;
            }
            red[t * 2] = a; red[t * 2 + 1] = aa;
        }
        for (int m = 0; m < 3; ++m) {
            const __bf16* src = (m == 0) ? wqt : (m == 1) ? wkt : wvt;
            for (int i = 0; i < 2; ++i) {
                int e = i * 256 + t, row = e >> 3, ch = e & 7;
                *(bf8*)&W[m][row][ch * 8] = *(const bf8*)(src + row * 64 + ch * 8);
            }
        }
        __syncthreads();
        if (t < 8) {
            float a = 0.f, aa = 0.f;
            for (int c = 0; c < 8; ++c) {
                a  += red[(c * 8 + t) * 2];
                aa += red[(c * 8 + t) * 2 + 1];
            }
            float mean = a * (1.f / 32768.f);
            float var = aa * (1.f / 32768.f) - mean * mean;
            sstat[t * 2 + 0] = mean;
            sstat[t * 2 + 1] = rsqrtf(var + 1e-3f);
        }
        __syncthreads();
        {
            int c4 = (t & 15) * 4, grp = c4 >> 3;
            float mean = sstat[grp * 2], rstd = sstat[grp * 2 + 1];
            float g0 = gamma[c4] * rstd, g1 = gamma[c4 + 1] * rstd,
                  g2 = gamma[c4 + 2] * rstd, g3 = gamma[c4 + 3] * rstd;
            float b0 = beta[c4], b1 = beta[c4 + 1], b2 = beta[c4 + 2], b3 = beta[c4 + 3];
            const float4* xb = (const float4*)(x + rowbase * 64);
            for (int i = 0; i < 4; ++i) {
                int row = (t >> 4) + i * 16;
                float4 v = xb[row * 16 + (t & 15)];
                bf4 hv;
                hv[0] = (__bf16)((v.x - mean) * g0 + b0);
                hv[1] = (__bf16)((v.y - mean) * g1 + b1);
                hv[2] = (__bf16)((v.z - mean) * g2 + b2);
                hv[3] = (__bf16)((v.w - mean) * g3 + b3);
                *(bf4*)&Hl[row][c4] = hv;
            }
        }
        __syncthreads();
        int lane = t & 63, wave = t >> 6, quad = lane >> 4, l15 = lane & 15;
        bf8 a0 = *(const bf8*)&Hl[wave * 16 + l15][quad * 8];
        bf8 a1 = *(const bf8*)&Hl[wave * 16 + l15][32 + quad * 8];
        for (int m = 0; m < 3; ++m) {
            const float* bias = (m == 0) ? bq : (m == 1) ? bk : bv;
            float sc = (m == 0) ? 0.125f * LOG2E : 1.0f;
            for (int tt = 0; tt < 4; ++tt) {
                int col = l15 + 16 * tt;
                bf8 b0 = *(const bf8*)&W[m][col][quad * 8];
                bf8 b1 = *(const bf8*)&W[m][col][32 + quad * 8];
                f4 acc = {0.f, 0.f, 0.f, 0.f};
                acc = mfma16(a0, b0, acc);
                acc = mfma16(a1, b1, acc);
                float bb = bias[col];
                if (m == 2) {
                    for (int r = 0; r < 4; ++r)
                        Vst[col][wave * 16 + quad * 4 + r] = (_Float16)(acc[r] + bb);
                } else {
                    __bf16* dst = (m == 0) ? q : k;
                    for (int r = 0; r < 4; ++r) {
                        float val = (acc[r] + bb) * sc;
                        dst[(rowbase + wave * 16 + quad * 4 + r) * 64 + col] = (__bf16)val;
                    }
                }
            }
        }
        __syncthreads();
        {   // tiled V^T writeout: vt[((b*256 + ktile)*64 + d)*16 + key%16]
            int d = t >> 2, seg = t & 3;
            h4 c0 = *(const h4*)&Vst[d][seg * 16 + 0];
            h4 c1 = *(const h4*)&Vst[d][seg * 16 + 4];
            h4 c2 = *(const h4*)&Vst[d][seg * 16 + 8];
            h4 c3 = *(const h4*)&Vst[d][seg * 16 + 12];
            h8 o0 = {c0[0], c0[1], c0[2], c0[3], c1[0], c1[1], c1[2], c1[3]};
            h8 o1 = {c2[0], c2[1], c2[2], c2[3], c3[0], c3[1], c3[2], c3[3]};
            _Float16* dst = vT + (((size_t)b * 256 + (tokbase >> 4) + seg) * 64 + d) * 16;
            *(h8*)dst = o0;
            *(h8*)(dst + 8) = o1;
        }
    }

    cg::this_grid().sync();

    // ---------------- Phase C: attention + projection + residual (R9 body) ----------------
    {
        _Float16 (*Om)[64][72] = (_Float16 (*)[64][72])(smem);
        float (*sS)[64] = (float (*)[64])(smem + 18432);
        __bf16 (*Wl)[72] = (__bf16 (*)[72])(smem + 18944);
        __bf16 (*Ol)[72] = (__bf16 (*)[72])(smem + 28160);
        float* red   = (float*)(smem + 37376);
        float* sstat = (float*)(smem + 37888);
        float* sg    = (float*)(smem + 37952);
        float* sb    = (float*)(smem + 38208);

        int qt = bid >> 3, b = bid & 7;
        int lane = t & 63, w = t >> 6, quad = lane >> 4, l15 = lane & 15;

        for (int i = 0; i < 2; ++i) {
            int e = i * 256 + t, row = e >> 3, ch = e & 7;
            *(bf8*)&Wl[row][ch * 8] = *(const bf8*)(wpt + row * 64 + ch * 8);
        }
        if (t < 64) { sg[t] = gamma[t]; sb[t] = beta[t]; }
        if (t < 64) {
            int gi = t & 7, c = t >> 3;
            const float2* gp = (const float2*)gpart + (size_t)b * 512 + gi;
            float a = 0.f, aa = 0.f;
            for (int p = c * 8; p < c * 8 + 8; ++p) {
                float2 v = gp[(size_t)p * 8];
                a += v.x; aa += v.y;
            }
            red[t * 2] = a; red[t * 2 + 1] = aa;
        }

        const __bf16* qbase = q + ((size_t)b * NTOK + qt * 64) * 64;
        bf8 aq[4][2];
        for (int s = 0; s < 4; ++s) {
            const __bf16* r = qbase + (s * 16 + l15) * 64;
            aq[s][0] = *(const bf8*)(r + quad * 8);
            aq[s][1] = *(const bf8*)(r + 32 + quad * 8);
        }
        const __bf16* kr = k + ((size_t)b * NTOK + w * 1024 + l15) * 64;
        const _Float16* vr = vT + (size_t)b * 262144 + ((size_t)(w * 64) * 64 + l15) * 16 + quad * 4;

        f4 acc[4][4] = {};
        float li[4] = {0.f, 0.f, 0.f, 0.f};

        bf8 kf0 = *(const bf8*)(kr + quad * 8);
        bf8 kf1 = *(const bf8*)(kr + 32 + quad * 8);
        h4 vf0 = *(const h4*)(vr);
        h4 vf1 = *(const h4*)(vr + 256);
        h4 vf2 = *(const h4*)(vr + 512);
        h4 vf3 = *(const h4*)(vr + 768);

        #pragma unroll 1
        for (int it = 0; it < 64; ++it) {
            int nx = (it + 1) & 63;
            const __bf16* krn = kr + (size_t)nx * 1024;
            const _Float16* vrn = vr + (size_t)nx * 1024;
            bf8 nk0 = *(const bf8*)(krn + quad * 8);
            bf8 nk1 = *(const bf8*)(krn + 32 + quad * 8);
            h4 nv0 = *(const h4*)(vrn);
            h4 nv1 = *(const h4*)(vrn + 256);
            h4 nv2 = *(const h4*)(vrn + 512);
            h4 nv3 = *(const h4*)(vrn + 768);

            for (int s = 0; s < 4; ++s) {
                f4 St = {0.f, 0.f, 0.f, 0.f};
                St = mfma16(kf0, aq[s][0], St);
                St = mfma16(kf1, aq[s][1], St);
                h4 pf;
                for (int r = 0; r < 4; ++r) {
                    float pv = __builtin_amdgcn_exp2f(St[r]);
                    li[s] += pv;
                    pf[r] = (_Float16)pv;
                }
                acc[s][0] = mfma16h(vf0, pf, acc[s][0]);
                acc[s][1] = mfma16h(vf1, pf, acc[s][1]);
                acc[s][2] = mfma16h(vf2, pf, acc[s][2]);
                acc[s][3] = mfma16h(vf3, pf, acc[s][3]);
            }
            kf0 = nk0; kf1 = nk1;
            vf0 = nv0; vf1 = nv1; vf2 = nv2; vf3 = nv3;
        }

        for (int s = 0; s < 4; ++s) {
            li[s] += __shfl_xor(li[s], 16);
            li[s] += __shfl_xor(li[s], 32);
        }

        if (w >= 2) {
            for (int s = 0; s < 4; ++s) {
                for (int td = 0; td < 4; ++td) {
                    h4 o4;
                    for (int r = 0; r < 4; ++r) o4[r] = (_Float16)acc[s][td][r];
                    *(h4*)&Om[w - 2][s * 16 + l15][td * 16 + quad * 4] = o4;
                }
                if (quad == 0) sS[w - 2][s * 16 + l15] = li[s];
            }
        }
        __syncthreads();
        if (t < 8) {
            float a = 0.f, aa = 0.f;
            for (int c = 0; c < 8; ++c) {
                a  += red[(c * 8 + t) * 2];
                aa += red[(c * 8 + t) * 2 + 1];
            }
            float mean = a * (1.f / 32768.f);
            float var = aa * (1.f / 32768.f) - mean * mean;
            sstat[t * 2 + 0] = mean;
            sstat[t * 2 + 1] = rsqrtf(var + 1e-3f);
        }
        if (w < 2) {
            for (int s = 0; s < 4; ++s) {
                for (int td = 0; td < 4; ++td) {
                    h4 o4 = *(const h4*)&Om[w][s * 16 + l15][td * 16 + quad * 4];
                    for (int r = 0; r < 4; ++r) acc[s][td][r] += (float)o4[r];
                }
                li[s] += sS[w][s * 16 + l15];
            }
        }
        __syncthreads();
        if (w < 2) {
            for (int s = 0; s < 4; ++s) {
                for (int td = 0; td < 4; ++td) {
                    h4 o4;
                    for (int r = 0; r < 4; ++r) o4[r] = (_Float16)acc[s][td][r];
                    *(h4*)&Om[w][s * 16 + l15][td * 16 + quad * 4] = o4;
                }
                if (quad == 0) sS[w][s * 16 + l15] = li[s];
            }
        }
        __syncthreads();
        {
            int qq = t >> 2, ds = (t & 3) * 16;
            float inv = 1.f / (sS[0][qq] + sS[1][qq]);
            h8 a0 = *(const h8*)&Om[0][qq][ds];
            h8 b0 = *(const h8*)&Om[0][qq][ds + 8];
            h8 a1 = *(const h8*)&Om[1][qq][ds];
            h8 b1 = *(const h8*)&Om[1][qq][ds + 8];
            bf8 olo, ohi;
            for (int j = 0; j < 8; ++j) {
                olo[j] = (__bf16)(((float)a0[j] + (float)a1[j]) * inv);
                ohi[j] = (__bf16)(((float)b0[j] + (float)b1[j]) * inv);
            }
            *(bf8*)&Ol[qq][ds] = olo;
            *(bf8*)&Ol[qq][ds + 8] = ohi;
        }
        __syncthreads();
        size_t rowbase = ((size_t)b * NTOK + qt * 64) + w * 16;
        bf8 a0 = *(const bf8*)&Ol[w * 16 + l15][quad * 8];
        bf8 a1 = *(const bf8*)&Ol[w * 16 + l15][32 + quad * 8];
        for (int tt = 0; tt < 4; ++tt) {
            int col = l15 + 16 * tt;
            bf8 b0 = *(const bf8*)&Wl[col][quad * 8];
            bf8 b1 = *(const bf8*)&Wl[col][32 + quad * 8];
            f4 pacc = {0.f, 0.f, 0.f, 0.f};
            pacc = mfma16(a0, b0, pacc);
            pacc = mfma16(a1, b1, pacc);
            int grp = col >> 3;
            float mean = sstat[grp * 2], gs = sg[col] * sstat[grp * 2 + 1], bs = sb[col];
            float bias = bp[col];
            for (int r = 0; r < 4; ++r) {
                size_t gi = (rowbase + quad * 4 + r) * 64 + col;
                float h = (x[gi] - mean) * gs + bs;
                out[gi] = pacc[r] + bias + h;
            }
        }
    }
}

// =================== fallback path: the proven R9 three-kernel pipeline ===================
__global__ __launch_bounds__(256) void pre_kernel(const float* __restrict__ wq,
                                                  const float* __restrict__ wk,
                                                  const float* __restrict__ wv,
                                                  const float* __restrict__ wp,
                                                  const float* __restrict__ x,
                                                  __bf16* __restrict__ wqt,
                                                  __bf16* __restrict__ wkt,
                                                  __bf16* __restrict__ wvt,
                                                  __bf16* __restrict__ wpt,
                                                  float* __restrict__ gpart) {
    int t = threadIdx.x;
    if (blockIdx.x < 4) {
        int m = blockIdx.x;
        const float* src = (m == 0) ? wq : (m == 1) ? wk : (m == 2) ? wv : wp;
        __bf16* dst      = (m == 0) ? wqt : (m == 1) ? wkt : (m == 2) ? wvt : wpt;
        __shared__ float s[64][65];
        for (int i = 0; i < 16; ++i) {
            int e = i * 256 + t;
            s[e >> 6][e & 63] = src[e];
        }
        __syncthreads();
        int o = t >> 2, seg = t & 3;
        for (int j = 0; j < 16; ++j) {
            int in = seg * 16 + j;
            dst[o * 64 + in] = (__bf16)s[in][o];
        }
        return;
    }
    int bid = blockIdx.x - 4;
    int b = bid >> 6, slab = bid & 63;
    const float4* xb = (const float4*)(x + (size_t)(b * NTOK + slab * 64) * CH);
    float s = 0.f, ss = 0.f;
    for (int i = 0; i < 4; ++i) {
        int row = (t >> 4) + i * 16;
        float4 v = xb[row * 16 + (t & 15)];
        s  += v.x + v.y + v.z + v.w;
        ss += v.x * v.x + v.y * v.y + v.z * v.z + v.w * v.w;
    }
    __shared__ float ls[256], lss[256];
    ls[t] = s; lss[t] = ss;
    __syncthreads();
    if (t < 8) {
        float a = 0.f, aa = 0.f;
        for (int p = 0; p < 16; ++p) {
            a  += ls[p * 16 + 2 * t]  + ls[p * 16 + 2 * t + 1];
            aa += lss[p * 16 + 2 * t] + lss[p * 16 + 2 * t + 1];
        }
        gpart[((b * 64 + slab) * 8 + t) * 2 + 0] = a;
        gpart[((b * 64 + slab) * 8 + t) * 2 + 1] = aa;
    }
}

__global__ __launch_bounds__(256) void qkv_gn(const float* __restrict__ x,
                                              const float* __restrict__ gpart,
                                              const float* __restrict__ gamma,
                                              const float* __restrict__ beta,
                                              const __bf16* __restrict__ wqt,
                                              const __bf16* __restrict__ wkt,
                                              const __bf16* __restrict__ wvt,
                                              const float* __restrict__ bq,
                                              const float* __restrict__ bk,
                                              const float* __restrict__ bv,
                                              __bf16* __restrict__ q,
                                              __bf16* __restrict__ k,
                                              _Float16* __restrict__ vT) {
    __shared__ __bf16 W[3][64][72];
    __shared__ __bf16 Hl[64][72];
    __shared__ _Float16 Vst[64][68];
    __shared__ float red[128];
    __shared__ float sstat[16];
    int t = threadIdx.x;
    size_t rowbase = (size_t)blockIdx.x * 64;
    int b = (int)(rowbase >> 12), tokbase = (int)(rowbase & 4095);
    if (t < 64) {
        int gi = t & 7, c = t >> 3;
        const float2* gp = (const float2*)gpart + (size_t)b * 512 + gi;
        float a = 0.f, aa = 0.f;
        for (int p = c * 8; p < c * 8 + 8; ++p) {
            float2 v = gp[(size_t)p * 8];
            a += v.x; aa += v.y;
        }
        red[t * 2] = a; red[t * 2 + 1] = aa;
    }
    for (int m = 0; m < 3; ++m) {
        const __bf16* src = (m == 0) ? wqt : (m == 1) ? wkt : wvt;
        for (int i = 0; i < 2; ++i) {
            int e = i * 256 + t, row = e >> 3, ch = e & 7;
            *(bf8*)&W[m][row][ch * 8] = *(const bf8*)(src + row * 64 + ch * 8);
        }
    }
    __syncthreads();
    if (t < 8) {
        float a = 0.f, aa = 0.f;
        for (int c = 0; c < 8; ++c) {
            a  += red[(c * 8 + t) * 2];
            aa += red[(c * 8 + t) * 2 + 1];
        }
        float mean = a * (1.f / 32768.f);
        float var = aa * (1.f / 32768.f) - mean * mean;
        sstat[t * 2 + 0] = mean;
        sstat[t * 2 + 1] = rsqrtf(var + 1e-3f);
    }
    __syncthreads();
    {
        int c4 = (t & 15) * 4, grp = c4 >> 3;
        float mean = sstat[grp * 2], rstd = sstat[grp * 2 + 1];
        float g0 = gamma[c4] * rstd, g1 = gamma[c4 + 1] * rstd,
              g2 = gamma[c4 + 2] * rstd, g3 = gamma[c4 + 3] * rstd;
        float b0 = beta[c4], b1 = beta[c4 + 1], b2 = beta[c4 + 2], b3 = beta[c4 + 3];
        const float4* xb = (const float4*)(x + rowbase * 64);
        for (int i = 0; i < 4; ++i) {
            int row = (t >> 4) + i * 16;
            float4 v = xb[row * 16 + (t & 15)];
            bf4 hv;
            hv[0] = (__bf16)((v.x - mean) * g0 + b0);
            hv[1] = (__bf16)((v.y - mean) * g1 + b1);
            hv[2] = (__bf16)((v.z - mean) * g2 + b2);
            hv[3] = (__bf16)((v.w - mean) * g3 + b3);
            *(bf4*)&Hl[row][c4] = hv;
        }
    }
    __syncthreads();
    int lane = t & 63, wave = t >> 6, quad = lane >> 4, l15 = lane & 15;
    bf8 a0 = *(const bf8*)&Hl[wave * 16 + l15][quad * 8];
    bf8 a1 = *(const bf8*)&Hl[wave * 16 + l15][32 + quad * 8];
    for (int m = 0; m < 3; ++m) {
        const float* bias = (m == 0) ? bq : (m == 1) ? bk : bv;
        float sc = (m == 0) ? 0.125f * LOG2E : 1.0f;
        for (int tt = 0; tt < 4; ++tt) {
            int col = l15 + 16 * tt;
            bf8 b0 = *(const bf8*)&W[m][col][quad * 8];
            bf8 b1 = *(const bf8*)&W[m][col][32 + quad * 8];
            f4 acc = {0.f, 0.f, 0.f, 0.f};
            acc = mfma16(a0, b0, acc);
            acc = mfma16(a1, b1, acc);
            float bb = bias[col];
            if (m == 2) {
                for (int r = 0; r < 4; ++r)
                    Vst[col][wave * 16 + quad * 4 + r] = (_Float16)(acc[r] + bb);
            } else {
                __bf16* dst = (m == 0) ? q : k;
                for (int r = 0; r < 4; ++r) {
                    float val = (acc[r] + bb) * sc;
                    dst[(rowbase + wave * 16 + quad * 4 + r) * 64 + col] = (__bf16)val;
                }
            }
        }
    }
    __syncthreads();
    {
        int d = t >> 2, seg = t & 3;
        h4 c0 = *(const h4*)&Vst[d][seg * 16 + 0];
        h4 c1 = *(const h4*)&Vst[d][seg * 16 + 4];
        h4 c2 = *(const h4*)&Vst[d][seg * 16 + 8];
        h4 c3 = *(const h4*)&Vst[d][seg * 16 + 12];
        h8 o0 = {c0[0], c0[1], c0[2], c0[3], c1[0], c1[1], c1[2], c1[3]};
        h8 o1 = {c2[0], c2[1], c2[2], c2[3], c3[0], c3[1], c3[2], c3[3]};
        _Float16* dst = vT + (((size_t)b * 256 + (tokbase >> 4) + seg) * 64 + d) * 16;
        *(h8*)dst = o0;
        *(h8*)(dst + 8) = o1;
    }
}

__global__ __launch_bounds__(256, 2) void attn_final(const __bf16* __restrict__ q,
                                                     const __bf16* __restrict__ k,
                                                     const _Float16* __restrict__ vt,
                                                     const __bf16* __restrict__ wpt,
                                                     const float* __restrict__ bp,
                                                     const float* __restrict__ x,
                                                     const float* __restrict__ gpart,
                                                     const float* __restrict__ gamma,
                                                     const float* __restrict__ beta,
                                                     float* __restrict__ out) {
    __shared__ _Float16 Om[2][64][72];
    __shared__ float sS[2][64];
    __shared__ __bf16 Wl[64][72];
    __shared__ __bf16 Ol[64][72];
    __shared__ float red[128];
    __shared__ float sstat[16], sg[64], sb[64];

    int bid = blockIdx.x;
    int qt = bid >> 3, b = bid & 7;
    int t = threadIdx.x, lane = t & 63, w = t >> 6, quad = lane >> 4, l15 = lane & 15;

    for (int i = 0; i < 2; ++i) {
        int e = i * 256 + t, row = e >> 3, ch = e & 7;
        *(bf8*)&Wl[row][ch * 8] = *(const bf8*)(wpt + row * 64 + ch * 8);
    }
    if (t < 64) { sg[t] = gamma[t]; sb[t] = beta[t]; }
    if (t < 64) {
        int gi = t & 7, c = t >> 3;
        const float2* gp = (const float2*)gpart + (size_t)b * 512 + gi;
        float a = 0.f, aa = 0.f;
        for (int p = c * 8; p < c * 8 + 8; ++p) {
            float2 v = gp[(size_t)p * 8];
            a += v.x; aa += v.y;
        }
        red[t * 2] = a; red[t * 2 + 1] = aa;
    }

    const __bf16* qbase = q + ((size_t)b * NTOK + qt * 64) * 64;
    bf8 aq[4][2];
    for (int s = 0; s < 4; ++s) {
        const __bf16* r = qbase + (s * 16 + l15) * 64;
        aq[s][0] = *(const bf8*)(r + quad * 8);
        aq[s][1] = *(const bf8*)(r + 32 + quad * 8);
    }
    const __bf16* kr = k + ((size_t)b * NTOK + w * 1024 + l15) * 64;
    const _Float16* vr = vt + (size_t)b * 262144 + ((size_t)(w * 64) * 64 + l15) * 16 + quad * 4;

    f4 acc[4][4] = {};
    float li[4] = {0.f, 0.f, 0.f, 0.f};

    bf8 kf0 = *(const bf8*)(kr + quad * 8);
    bf8 kf1 = *(const bf8*)(kr + 32 + quad * 8);
    h4 vf0 = *(const h4*)(vr);
    h4 vf1 = *(const h4*)(vr + 256);
    h4 vf2 = *(const h4*)(vr + 512);
    h4 vf3 = *(const h4*)(vr + 768);

    #pragma unroll 1
    for (int it = 0; it < 64; ++it) {
        int nx = (it + 1) & 63;
        const __bf16* krn = kr + (size_t)nx * 1024;
        const _Float16* vrn = vr + (size_t)nx * 1024;
        bf8 nk0 = *(const bf8*)(krn + quad * 8);
        bf8 nk1 = *(const bf8*)(krn + 32 + quad * 8);
        h4 nv0 = *(const h4*)(vrn);
        h4 nv1 = *(const h4*)(vrn + 256);
        h4 nv2 = *(const h4*)(vrn + 512);
        h4 nv3 = *(const h4*)(vrn + 768);

        for (int s = 0; s < 4; ++s) {
            f4 St = {0.f, 0.f, 0.f, 0.f};
            St = mfma16(kf0, aq[s][0], St);
            St = mfma16(kf1, aq[s][1], St);
            h4 pf;
            for (int r = 0; r < 4; ++r) {
                float pv = __builtin_amdgcn_exp2f(St[r]);
                li[s] += pv;
                pf[r] = (_Float16)pv;
            }
            acc[s][0] = mfma16h(vf0, pf, acc[s][0]);
            acc[s][1] = mfma16h(vf1, pf, acc[s][1]);
            acc[s][2] = mfma16h(vf2, pf, acc[s][2]);
            acc[s][3] = mfma16h(vf3, pf, acc[s][3]);
        }
        kf0 = nk0; kf1 = nk1;
        vf0 = nv0; vf1 = nv1; vf2 = nv2; vf3 = nv3;
    }

    for (int s = 0; s < 4; ++s) {
        li[s] += __shfl_xor(li[s], 16);
        li[s] += __shfl_xor(li[s], 32);
    }

    if (w >= 2) {
        for (int s = 0; s < 4; ++s) {
            for (int td = 0; td < 4; ++td) {
                h4 o4;
                for (int r = 0; r < 4; ++r) o4[r] = (_Float16)acc[s][td][r];
                *(h4*)&Om[w - 2][s * 16 + l15][td * 16 + quad * 4] = o4;
            }
            if (quad == 0) sS[w - 2][s * 16 + l15] = li[s];
        }
    }
    __syncthreads();
    if (t < 8) {
        float a = 0.f, aa = 0.f;
        for (int c = 0; c < 8; ++c) {
            a  += red[(c * 8 + t) * 2];
            aa += red[(c * 8 + t) * 2 + 1];
        }
        float mean = a * (1.f / 32768.f);
        float var = aa * (1.f / 32768.f) - mean * mean;
        sstat[t * 2 + 0] = mean;
        sstat[t * 2 + 1] = rsqrtf(var + 1e-3f);
    }
    if (w < 2) {
        for (int s = 0; s < 4; ++s) {
            for (int td = 0; td < 4; ++td) {
                h4 o4 = *(const h4*)&Om[w][s * 16 + l15][td * 16 + quad * 4];
                for (int r = 0; r < 4; ++r) acc[s][td][r] += (float)o4[r];
            }
            li[s] += sS[w][s * 16 + l15];
        }
    }
    __syncthreads();
    if (w < 2) {
        for (int s = 0; s < 4; ++s) {
            for (int td = 0; td < 4; ++td) {
                h4 o4;
                for (int r = 0; r < 4; ++r) o4[r] = (_Float16)acc[s][td][r];
                *(h4*)&Om[w][s * 16 + l15][td * 16 + quad * 4] = o4;
            }
            if (quad == 0) sS[w][s * 16 + l15] = li[s];
        }
    }
    __syncthreads();
    {
        int qq = t >> 2, ds = (t & 3) * 16;
        float inv = 1.f / (sS[0][qq] + sS[1][qq]);
        h8 a0 = *(const h8*)&Om[0][qq][ds];
        h8 b0 = *(const h8*)&Om[0][qq][ds + 8];
        h8 a1 = *(const h8*)&Om[1][qq][ds];
        h8 b1 = *(const h8*)&Om[1][qq][ds + 8];
        bf8 olo, ohi;
        for (int j = 0; j < 8; ++j) {
            olo[j] = (__bf16)(((float)a0[j] + (float)a1[j]) * inv);
            ohi[j] = (__bf16)(((float)b0[j] + (float)b1[j]) * inv);
        }
        *(bf8*)&Ol[qq][ds] = olo;
        *(bf8*)&Ol[qq][ds + 8] = ohi;
    }
    __syncthreads();
    size_t rowbase = ((size_t)b * NTOK + qt * 64) + w * 16;
    bf8 a0 = *(const bf8*)&Ol[w * 16 + l15][quad * 8];
    bf8 a1 = *(const bf8*)&Ol[w * 16 + l15][32 + quad * 8];
    for (int tt = 0; tt < 4; ++tt) {
        int col = l15 + 16 * tt;
        bf8 b0 = *(const bf8*)&Wl[col][quad * 8];
        bf8 b1 = *(const bf8*)&Wl[col][32 + quad * 8];
        f4 pacc = {0.f, 0.f, 0.f, 0.f};
        pacc = mfma16(a0, b0, pacc);
        pacc = mfma16(a1, b1, pacc);
        int grp = col >> 3;
        float mean = sstat[grp * 2], gs = sg[col] * sstat[grp * 2 + 1], bs = sb[col];
        float bias = bp[col];
        for (int r = 0; r < 4; ++r) {
            size_t gi = (rowbase + quad * 4 + r) * 64 + col;
            float h = (x[gi] - mean) * gs + bs;
            out[gi] = pacc[r] + bias + h;
        }
    }
}

extern "C" void kernel_launch(void* const* d_in, const int* in_sizes, int n_in,
                              void* d_out, int out_size, void* d_ws, size_t ws_size,
                              hipStream_t stream) {
    const float* x     = (const float*)d_in[0];
    const float* gamma = (const float*)d_in[1];
    const float* beta  = (const float*)d_in[2];
    const float* wq    = (const float*)d_in[3];
    const float* bq    = (const float*)d_in[4];
    const float* wk    = (const float*)d_in[5];
    const float* bk    = (const float*)d_in[6];
    const float* wv    = (const float*)d_in[7];
    const float* bv    = (const float*)d_in[8];
    const float* wp    = (const float*)d_in[9];
    const float* bp    = (const float*)d_in[10];
    float* out = (float*)d_out;

    char* ws = (char*)d_ws;
    const size_t MB = 1024 * 1024;
    __bf16*   qb   = (__bf16*)(ws);                 // 4 MB
    __bf16*   kb   = (__bf16*)(ws + 4 * MB);        // 4 MB
    _Float16* vtb  = (_Float16*)(ws + 8 * MB);      // 4 MB (tiled V^T fp16)
    __bf16*   wqt  = (__bf16*)(ws + 12 * MB);
    __bf16*   wkt  = (__bf16*)(ws + 12 * MB + 8192);
    __bf16*   wvt  = (__bf16*)(ws + 12 * MB + 16384);
    __bf16*   wpt  = (__bf16*)(ws + 12 * MB + 24576);
    float*    gpart = (float*)(ws + 12 * MB + 32768);   // 32 KB

    void* args[] = {(void*)&x, (void*)&gamma, (void*)&beta,
                    (void*)&wq, (void*)&bq, (void*)&wk, (void*)&bk,
                    (void*)&wv, (void*)&bv, (void*)&wp, (void*)&bp,
                    (void*)&qb, (void*)&kb, (void*)&vtb,
                    (void*)&wqt, (void*)&wkt, (void*)&wvt, (void*)&wpt,
                    (void*)&gpart, (void*)&out};
    hipError_t err = hipLaunchCooperativeKernel((void*)fused_all, dim3(512), dim3(256),
                                                args, 0, stream);
    if (err != hipSuccess) {
        // fallback: proven three-kernel pipeline (R9)
        pre_kernel<<<516, 256, 0, stream>>>(wq, wk, wv, wp, x, wqt, wkt, wvt, wpt, gpart);
        qkv_gn<<<512, 256, 0, stream>>>(x, gpart, gamma, beta, wqt, wkt, wvt,
                                        bq, bk, bv, qb, kb, vtb);
        attn_final<<<512, 256, 0, stream>>>(qb, kb, vtb, wpt, bp, x, gpart, gamma, beta, out);
    }
}

// Round 11
// 183.128 us; speedup vs baseline: 1.6002x; 1.6002x over previous
//
#include <hip/hip_runtime.h>

#define NTOK 4096
#define CH 64
#define LOG2E 1.4426950408889634f

typedef __bf16 bf8 __attribute__((ext_vector_type(8)));
typedef __bf16 bf4 __attribute__((ext_vector_type(4)));
typedef _Float16 h8 __attribute__((ext_vector_type(8)));
typedef _Float16 h4 __attribute__((ext_vector_type(4)));
typedef float f4 __attribute__((ext_vector_type(4)));

__device__ __forceinline__ f4 mfma16(bf8 a, bf8 b, f4 c) {
    return __builtin_amdgcn_mfma_f32_16x16x32_bf16(a, b, c, 0, 0, 0);
}
__device__ __forceinline__ f4 mfma16h(h4 a, h4 b, f4 c) {
    return __builtin_amdgcn_mfma_f32_16x16x16f16(a, b, c, 0, 0, 0);
}

// ---------------- fused pre-pass: blocks 0..3 = weight transpose; 4..515 = GN partials ----
__global__ __launch_bounds__(256) void pre_kernel(const float* __restrict__ wq,
                                                  const float* __restrict__ wk,
                                                  const float* __restrict__ wv,
                                                  const float* __restrict__ wp,
                                                  const float* __restrict__ x,
                                                  __bf16* __restrict__ wqt,
                                                  __bf16* __restrict__ wkt,
                                                  __bf16* __restrict__ wvt,
                                                  __bf16* __restrict__ wpt,
                                                  float* __restrict__ gpart) {
    int t = threadIdx.x;
    if (blockIdx.x < 4) {   // weight transpose + bf16 convert
        int m = blockIdx.x;
        const float* src = (m == 0) ? wq : (m == 1) ? wk : (m == 2) ? wv : wp;
        __bf16* dst      = (m == 0) ? wqt : (m == 1) ? wkt : (m == 2) ? wvt : wpt;
        __shared__ float s[64][65];
        for (int i = 0; i < 16; ++i) {
            int e = i * 256 + t;
            s[e >> 6][e & 63] = src[e];
        }
        __syncthreads();
        int o = t >> 2, seg = t & 3;
        for (int j = 0; j < 16; ++j) {
            int in = seg * 16 + j;
            dst[o * 64 + in] = (__bf16)s[in][o];
        }
        return;
    }
    // GN partial sums: 512 blocks = 8b x 64 slabs of 64 rows
    int bid = blockIdx.x - 4;
    int b = bid >> 6, slab = bid & 63;
    const float4* xb = (const float4*)(x + (size_t)(b * NTOK + slab * 64) * CH);
    float s = 0.f, ss = 0.f;
    for (int i = 0; i < 4; ++i) {
        int row = (t >> 4) + i * 16;
        float4 v = xb[row * 16 + (t & 15)];
        s  += v.x + v.y + v.z + v.w;
        ss += v.x * v.x + v.y * v.y + v.z * v.z + v.w * v.w;
    }
    __shared__ float ls[256], lss[256];
    ls[t] = s; lss[t] = ss;
    __syncthreads();
    if (t < 8) {
        float a = 0.f, aa = 0.f;
        for (int p = 0; p < 16; ++p) {
            a  += ls[p * 16 + 2 * t]  + ls[p * 16 + 2 * t + 1];
            aa += lss[p * 16 + 2 * t] + lss[p * 16 + 2 * t + 1];
        }
        gpart[((b * 64 + slab) * 8 + t) * 2 + 0] = a;
        gpart[((b * 64 + slab) * 8 + t) * 2 + 1] = aa;
    }
}

// ---------------- fused GN + QKV projection (grid 512, 64 rows/block) --------------------
__global__ __launch_bounds__(256) void qkv_gn(const float* __restrict__ x,
                                              const float* __restrict__ gpart,
                                              const float* __restrict__ gamma,
                                              const float* __restrict__ beta,
                                              const __bf16* __restrict__ wqt,
                                              const __bf16* __restrict__ wkt,
                                              const __bf16* __restrict__ wvt,
                                              const float* __restrict__ bq,
                                              const float* __restrict__ bk,
                                              const float* __restrict__ bv,
                                              __bf16* __restrict__ q,
                                              __bf16* __restrict__ k,
                                              _Float16* __restrict__ vT) {
    __shared__ __bf16 W[3][64][72];
    __shared__ __bf16 Hl[64][72];
    __shared__ _Float16 Vst[64][68];
    __shared__ float red[128];
    __shared__ float sstat[16];
    int t = threadIdx.x;
    size_t rowbase = (size_t)blockIdx.x * 64;
    int b = (int)(rowbase >> 12), tokbase = (int)(rowbase & 4095);
    if (t < 64) {
        int gi = t & 7, c = t >> 3;
        const float2* gp = (const float2*)gpart + (size_t)b * 512 + gi;
        float a = 0.f, aa = 0.f;
        for (int p = c * 8; p < c * 8 + 8; ++p) {
            float2 v = gp[(size_t)p * 8];
            a += v.x; aa += v.y;
        }
        red[t * 2] = a; red[t * 2 + 1] = aa;
    }
    for (int m = 0; m < 3; ++m) {
        const __bf16* src = (m == 0) ? wqt : (m == 1) ? wkt : wvt;
        for (int i = 0; i < 2; ++i) {
            int e = i * 256 + t, row = e >> 3, ch = e & 7;
            *(bf8*)&W[m][row][ch * 8] = *(const bf8*)(src + row * 64 + ch * 8);
        }
    }
    __syncthreads();
    if (t < 8) {
        float a = 0.f, aa = 0.f;
        for (int c = 0; c < 8; ++c) {
            a  += red[(c * 8 + t) * 2];
            aa += red[(c * 8 + t) * 2 + 1];
        }
        float mean = a * (1.f / 32768.f);
        float var = aa * (1.f / 32768.f) - mean * mean;
        sstat[t * 2 + 0] = mean;
        sstat[t * 2 + 1] = rsqrtf(var + 1e-3f);
    }
    __syncthreads();
    {
        int c4 = (t & 15) * 4, grp = c4 >> 3;
        float mean = sstat[grp * 2], rstd = sstat[grp * 2 + 1];
        float g0 = gamma[c4] * rstd, g1 = gamma[c4 + 1] * rstd,
              g2 = gamma[c4 + 2] * rstd, g3 = gamma[c4 + 3] * rstd;
        float b0 = beta[c4], b1 = beta[c4 + 1], b2 = beta[c4 + 2], b3 = beta[c4 + 3];
        const float4* xb = (const float4*)(x + rowbase * 64);
        for (int i = 0; i < 4; ++i) {
            int row = (t >> 4) + i * 16;
            float4 v = xb[row * 16 + (t & 15)];
            bf4 hv;
            hv[0] = (__bf16)((v.x - mean) * g0 + b0);
            hv[1] = (__bf16)((v.y - mean) * g1 + b1);
            hv[2] = (__bf16)((v.z - mean) * g2 + b2);
            hv[3] = (__bf16)((v.w - mean) * g3 + b3);
            *(bf4*)&Hl[row][c4] = hv;
        }
    }
    __syncthreads();
    int lane = t & 63, wave = t >> 6, quad = lane >> 4, l15 = lane & 15;
    bf8 a0 = *(const bf8*)&Hl[wave * 16 + l15][quad * 8];
    bf8 a1 = *(const bf8*)&Hl[wave * 16 + l15][32 + quad * 8];
    for (int m = 0; m < 3; ++m) {
        const float* bias = (m == 0) ? bq : (m == 1) ? bk : bv;
        float sc = (m == 0) ? 0.125f * LOG2E : 1.0f;
        for (int tt = 0; tt < 4; ++tt) {
            int col = l15 + 16 * tt;
            bf8 b0 = *(const bf8*)&W[m][col][quad * 8];
            bf8 b1 = *(const bf8*)&W[m][col][32 + quad * 8];
            f4 acc = {0.f, 0.f, 0.f, 0.f};
            acc = mfma16(a0, b0, acc);
            acc = mfma16(a1, b1, acc);
            float bb = bias[col];
            if (m == 2) {
                for (int r = 0; r < 4; ++r)
                    Vst[col][wave * 16 + quad * 4 + r] = (_Float16)(acc[r] + bb);
            } else {
                __bf16* dst = (m == 0) ? q : k;
                for (int r = 0; r < 4; ++r) {
                    float val = (acc[r] + bb) * sc;
                    dst[(rowbase + wave * 16 + quad * 4 + r) * 64 + col] = (__bf16)val;
                }
            }
        }
    }
    __syncthreads();
    {   // tiled V^T writeout: vt[((b*256 + ktile)*64 + d)*16 + key%16]
        int d = t >> 2, seg = t & 3;
        h4 c0 = *(const h4*)&Vst[d][seg * 16 + 0];
        h4 c1 = *(const h4*)&Vst[d][seg * 16 + 4];
        h4 c2 = *(const h4*)&Vst[d][seg * 16 + 8];
        h4 c3 = *(const h4*)&Vst[d][seg * 16 + 12];
        h8 o0 = {c0[0], c0[1], c0[2], c0[3], c1[0], c1[1], c1[2], c1[3]};
        h8 o1 = {c2[0], c2[1], c2[2], c2[3], c3[0], c3[1], c3[2], c3[3]};
        _Float16* dst = vT + (((size_t)b * 256 + (tokbase >> 4) + seg) * 64 + d) * 16;
        *(h8*)dst = o0;
        *(h8*)(dst + 8) = o1;
    }
}

// ---------------- fused attention + output projection + residual -------------------------
// grid 1024 = (qt*2+qh)*8 + b ; block 256 = 4 waves; block owns 32 q-rows, wave owns
// 1024-key chunk (64 iters x 16 keys, s-loop of 2 q-subtiles). 4 blocks/CU resident.
// Epilogue: 3-phase pairwise merge -> normalize -> wp proj + bias + GN residual.
__global__ __launch_bounds__(256, 2) void attn_final(const __bf16* __restrict__ q,
                                                     const __bf16* __restrict__ k,
                                                     const _Float16* __restrict__ vt,
                                                     const __bf16* __restrict__ wpt,
                                                     const float* __restrict__ bp,
                                                     const float* __restrict__ x,
                                                     const float* __restrict__ gpart,
                                                     const float* __restrict__ gamma,
                                                     const float* __restrict__ beta,
                                                     float* __restrict__ out) {
    __shared__ _Float16 Om[2][32][72];   // 9216 B
    __shared__ float sS[2][32];
    __shared__ __bf16 Wl[64][72];        // 9216 B
    __shared__ __bf16 Ol[32][72];        // 4608 B
    __shared__ float red[128];
    __shared__ float sstat[16], sg[64], sb[64];

    int bid = blockIdx.x;
    int b = bid & 7;
    int qh = (bid >> 3) & 1;
    int qt = bid >> 4;
    int qrow0 = qt * 64 + qh * 32;
    int t = threadIdx.x, lane = t & 63, w = t >> 6, quad = lane >> 4, l15 = lane & 15;

    // stage projection weights + gamma/beta + GN stat partials
    for (int i = 0; i < 2; ++i) {
        int e = i * 256 + t, row = e >> 3, ch = e & 7;
        *(bf8*)&Wl[row][ch * 8] = *(const bf8*)(wpt + row * 64 + ch * 8);
    }
    if (t < 64) { sg[t] = gamma[t]; sb[t] = beta[t]; }
    if (t < 64) {
        int gi = t & 7, c = t >> 3;
        const float2* gp = (const float2*)gpart + (size_t)b * 512 + gi;
        float a = 0.f, aa = 0.f;
        for (int p = c * 8; p < c * 8 + 8; ++p) {
            float2 v = gp[(size_t)p * 8];
            a += v.x; aa += v.y;
        }
        red[t * 2] = a; red[t * 2 + 1] = aa;
    }

    const __bf16* qbase = q + ((size_t)b * NTOK + qrow0) * 64;
    bf8 aq[2][2];
    for (int s = 0; s < 2; ++s) {
        const __bf16* r = qbase + (s * 16 + l15) * 64;
        aq[s][0] = *(const bf8*)(r + quad * 8);
        aq[s][1] = *(const bf8*)(r + 32 + quad * 8);
    }
    const __bf16* kbase   = k  + (size_t)b * NTOK * 64;
    const _Float16* vbase = vt + (size_t)b * 262144;

    f4 acc[2][4] = {};
    float li[2] = {0.f, 0.f};

    for (int it = 0; it < 64; ++it) {
        int key0 = w * 1024 + it * 16;             // this wave's 16-key tile
        const __bf16* kr = kbase + (size_t)(key0 + l15) * 64;
        bf8 kf0 = *(const bf8*)(kr + quad * 8);
        bf8 kf1 = *(const bf8*)(kr + 32 + quad * 8);
        int ktile = w * 64 + it;
        h4 vf0 = *(const h4*)(vbase + ((size_t)ktile * 64 +  0 + l15) * 16 + quad * 4);
        h4 vf1 = *(const h4*)(vbase + ((size_t)ktile * 64 + 16 + l15) * 16 + quad * 4);
        h4 vf2 = *(const h4*)(vbase + ((size_t)ktile * 64 + 32 + l15) * 16 + quad * 4);
        h4 vf3 = *(const h4*)(vbase + ((size_t)ktile * 64 + 48 + l15) * 16 + quad * 4);

        for (int s = 0; s < 2; ++s) {
            f4 St = {0.f, 0.f, 0.f, 0.f};
            St = mfma16(kf0, aq[s][0], St);
            St = mfma16(kf1, aq[s][1], St);
            h4 pf;
            for (int r = 0; r < 4; ++r) {
                float pv = __builtin_amdgcn_exp2f(St[r]);
                li[s] += pv;
                pf[r] = (_Float16)pv;
            }
            acc[s][0] = mfma16h(vf0, pf, acc[s][0]);
            acc[s][1] = mfma16h(vf1, pf, acc[s][1]);
            acc[s][2] = mfma16h(vf2, pf, acc[s][2]);
            acc[s][3] = mfma16h(vf3, pf, acc[s][3]);
        }
    }

    // quad-reduce li
    for (int s = 0; s < 2; ++s) {
        li[s] += __shfl_xor(li[s], 16);
        li[s] += __shfl_xor(li[s], 32);
    }

    // 3-phase pairwise merge
    if (w >= 2) {   // phase 1: waves 2,3 deposit
        for (int s = 0; s < 2; ++s) {
            for (int td = 0; td < 4; ++td) {
                h4 o4;
                for (int r = 0; r < 4; ++r) o4[r] = (_Float16)acc[s][td][r];
                *(h4*)&Om[w - 2][s * 16 + l15][td * 16 + quad * 4] = o4;
            }
            if (quad == 0) sS[w - 2][s * 16 + l15] = li[s];
        }
    }
    __syncthreads();
    if (t < 8) {    // GN stats finalize (red visible now)
        float a = 0.f, aa = 0.f;
        for (int c = 0; c < 8; ++c) {
            a  += red[(c * 8 + t) * 2];
            aa += red[(c * 8 + t) * 2 + 1];
        }
        float mean = a * (1.f / 32768.f);
        float var = aa * (1.f / 32768.f) - mean * mean;
        sstat[t * 2 + 0] = mean;
        sstat[t * 2 + 1] = rsqrtf(var + 1e-3f);
    }
    if (w < 2) {    // waves 0,1 absorb
        for (int s = 0; s < 2; ++s) {
            for (int td = 0; td < 4; ++td) {
                h4 o4 = *(const h4*)&Om[w][s * 16 + l15][td * 16 + quad * 4];
                for (int r = 0; r < 4; ++r) acc[s][td][r] += (float)o4[r];
            }
            li[s] += sS[w][s * 16 + l15];
        }
    }
    __syncthreads();
    if (w < 2) {    // phase 2: deposit pair-sums
        for (int s = 0; s < 2; ++s) {
            for (int td = 0; td < 4; ++td) {
                h4 o4;
                for (int r = 0; r < 4; ++r) o4[r] = (_Float16)acc[s][td][r];
                *(h4*)&Om[w][s * 16 + l15][td * 16 + quad * 4] = o4;
            }
            if (quad == 0) sS[w][s * 16 + l15] = li[s];
        }
    }
    __syncthreads();
    if (t < 128) {  // phase 3: combine + normalize into Ol (32 q-rows)
        int qq = t >> 2, ds = (t & 3) * 16;
        float inv = 1.f / (sS[0][qq] + sS[1][qq]);
        h8 a0 = *(const h8*)&Om[0][qq][ds];
        h8 b0 = *(const h8*)&Om[0][qq][ds + 8];
        h8 a1 = *(const h8*)&Om[1][qq][ds];
        h8 b1 = *(const h8*)&Om[1][qq][ds + 8];
        bf8 olo, ohi;
        for (int j = 0; j < 8; ++j) {
            olo[j] = (__bf16)(((float)a0[j] + (float)a1[j]) * inv);
            ohi[j] = (__bf16)(((float)b0[j] + (float)b1[j]) * inv);
        }
        *(bf8*)&Ol[qq][ds] = olo;
        *(bf8*)&Ol[qq][ds + 8] = ohi;
    }
    __syncthreads();
    // epilogue: out = Ol @ wp^T + bp + GN(x) ; waves 0,1 cover the 32 rows
    if (w < 2) {
        size_t rowbase = ((size_t)b * NTOK + qrow0) + w * 16;
        bf8 a0 = *(const bf8*)&Ol[w * 16 + l15][quad * 8];
        bf8 a1 = *(const bf8*)&Ol[w * 16 + l15][32 + quad * 8];
        for (int tt = 0; tt < 4; ++tt) {
            int col = l15 + 16 * tt;
            bf8 b0 = *(const bf8*)&Wl[col][quad * 8];
            bf8 b1 = *(const bf8*)&Wl[col][32 + quad * 8];
            f4 pacc = {0.f, 0.f, 0.f, 0.f};
            pacc = mfma16(a0, b0, pacc);
            pacc = mfma16(a1, b1, pacc);
            int grp = col >> 3;
            float mean = sstat[grp * 2], gs = sg[col] * sstat[grp * 2 + 1], bs = sb[col];
            float bias = bp[col];
            for (int r = 0; r < 4; ++r) {
                size_t gi = (rowbase + quad * 4 + r) * 64 + col;
                float h = (x[gi] - mean) * gs + bs;
                out[gi] = pacc[r] + bias + h;
            }
        }
    }
}

extern "C" void kernel_launch(void* const* d_in, const int* in_sizes, int n_in,
                              void* d_out, int out_size, void* d_ws, size_t ws_size,
                              hipStream_t stream) {
    const float* x     = (const float*)d_in[0];
    const float* gamma = (const float*)d_in[1];
    const float* beta  = (const float*)d_in[2];
    const float* wq    = (const float*)d_in[3];
    const float* bq    = (const float*)d_in[4];
    const float* wk    = (const float*)d_in[5];
    const float* bk    = (const float*)d_in[6];
    const float* wv    = (const float*)d_in[7];
    const float* bv    = (const float*)d_in[8];
    const float* wp    = (const float*)d_in[9];
    const float* bp    = (const float*)d_in[10];
    float* out = (float*)d_out;

    char* ws = (char*)d_ws;
    const size_t MB = 1024 * 1024;
    __bf16*   qb   = (__bf16*)(ws);                 // 4 MB
    __bf16*   kb   = (__bf16*)(ws + 4 * MB);        // 4 MB
    _Float16* vtb  = (_Float16*)(ws + 8 * MB);      // 4 MB (tiled V^T fp16)
    __bf16*   wqt  = (__bf16*)(ws + 12 * MB);
    __bf16*   wkt  = (__bf16*)(ws + 12 * MB + 8192);
    __bf16*   wvt  = (__bf16*)(ws + 12 * MB + 16384);
    __bf16*   wpt  = (__bf16*)(ws + 12 * MB + 24576);
    float*    gpart = (float*)(ws + 12 * MB + 32768);   // 32 KB

    pre_kernel<<<516, 256, 0, stream>>>(wq, wk, wv, wp, x, wqt, wkt, wvt, wpt, gpart);
    qkv_gn<<<512, 256, 0, stream>>>(x, gpart, gamma, beta, wqt, wkt, wvt, bq, bk, bv, qb, kb, vtb);
    attn_final<<<1024, 256, 0, stream>>>(qb, kb, vtb, wpt, bp, x, gpart, gamma, beta, out);
}

// Round 12
// 136.421 us; speedup vs baseline: 2.1481x; 1.3424x over previous
//
#include <hip/hip_runtime.h>

#define NTOK 4096
#define CH 64
#define LOG2E 1.4426950408889634f

typedef __bf16 bf8 __attribute__((ext_vector_type(8)));
typedef __bf16 bf4 __attribute__((ext_vector_type(4)));
typedef _Float16 h8 __attribute__((ext_vector_type(8)));
typedef _Float16 h4 __attribute__((ext_vector_type(4)));
typedef float f4 __attribute__((ext_vector_type(4)));

__device__ __forceinline__ f4 mfma16(bf8 a, bf8 b, f4 c) {
    return __builtin_amdgcn_mfma_f32_16x16x32_bf16(a, b, c, 0, 0, 0);
}
__device__ __forceinline__ f4 mfma16h(h4 a, h4 b, f4 c) {
    return __builtin_amdgcn_mfma_f32_16x16x16f16(a, b, c, 0, 0, 0);
}

// ---------------- fused pre-pass: blocks 0..3 = weight transpose; 4..515 = GN partials ----
__global__ __launch_bounds__(256) void pre_kernel(const float* __restrict__ wq,
                                                  const float* __restrict__ wk,
                                                  const float* __restrict__ wv,
                                                  const float* __restrict__ wp,
                                                  const float* __restrict__ x,
                                                  __bf16* __restrict__ wqt,
                                                  __bf16* __restrict__ wkt,
                                                  __bf16* __restrict__ wvt,
                                                  __bf16* __restrict__ wpt,
                                                  float* __restrict__ gpart) {
    int t = threadIdx.x;
    if (blockIdx.x < 4) {   // weight transpose + bf16 convert
        int m = blockIdx.x;
        const float* src = (m == 0) ? wq : (m == 1) ? wk : (m == 2) ? wv : wp;
        __bf16* dst      = (m == 0) ? wqt : (m == 1) ? wkt : (m == 2) ? wvt : wpt;
        __shared__ float s[64][65];
        for (int i = 0; i < 16; ++i) {
            int e = i * 256 + t;
            s[e >> 6][e & 63] = src[e];
        }
        __syncthreads();
        int o = t >> 2, seg = t & 3;
        for (int j = 0; j < 16; ++j) {
            int in = seg * 16 + j;
            dst[o * 64 + in] = (__bf16)s[in][o];
        }
        return;
    }
    // GN partial sums: 512 blocks = 8b x 64 slabs of 64 rows
    int bid = blockIdx.x - 4;
    int b = bid >> 6, slab = bid & 63;
    const float4* xb = (const float4*)(x + (size_t)(b * NTOK + slab * 64) * CH);
    float s = 0.f, ss = 0.f;
    for (int i = 0; i < 4; ++i) {
        int row = (t >> 4) + i * 16;
        float4 v = xb[row * 16 + (t & 15)];
        s  += v.x + v.y + v.z + v.w;
        ss += v.x * v.x + v.y * v.y + v.z * v.z + v.w * v.w;
    }
    __shared__ float ls[256], lss[256];
    ls[t] = s; lss[t] = ss;
    __syncthreads();
    if (t < 8) {
        float a = 0.f, aa = 0.f;
        for (int p = 0; p < 16; ++p) {
            a  += ls[p * 16 + 2 * t]  + ls[p * 16 + 2 * t + 1];
            aa += lss[p * 16 + 2 * t] + lss[p * 16 + 2 * t + 1];
        }
        gpart[((b * 64 + slab) * 8 + t) * 2 + 0] = a;
        gpart[((b * 64 + slab) * 8 + t) * 2 + 1] = aa;
    }
}

// ---------------- fused GN + QKV projection (grid 512, 64 rows/block) --------------------
// V written fp16 in b128-fragment layout: vt[ktile][p(2)][lane(64)][u(2)][r(4)]
// where element (d = 32p+16u+(lane&15), key = (lane>>4)*4+r) of tile ktile.
__global__ __launch_bounds__(256) void qkv_gn(const float* __restrict__ x,
                                              const float* __restrict__ gpart,
                                              const float* __restrict__ gamma,
                                              const float* __restrict__ beta,
                                              const __bf16* __restrict__ wqt,
                                              const __bf16* __restrict__ wkt,
                                              const __bf16* __restrict__ wvt,
                                              const float* __restrict__ bq,
                                              const float* __restrict__ bk,
                                              const float* __restrict__ bv,
                                              __bf16* __restrict__ q,
                                              __bf16* __restrict__ k,
                                              _Float16* __restrict__ vT) {
    __shared__ __bf16 W[3][64][72];
    __shared__ __bf16 Hl[64][72];
    __shared__ _Float16 Vst[64][68];
    __shared__ float red[128];
    __shared__ float sstat[16];
    int t = threadIdx.x;
    size_t rowbase = (size_t)blockIdx.x * 64;
    int b = (int)(rowbase >> 12), tokbase = (int)(rowbase & 4095);
    if (t < 64) {
        int gi = t & 7, c = t >> 3;
        const float2* gp = (const float2*)gpart + (size_t)b * 512 + gi;
        float a = 0.f, aa = 0.f;
        for (int p = c * 8; p < c * 8 + 8; ++p) {
            float2 v = gp[(size_t)p * 8];
            a += v.x; aa += v.y;
        }
        red[t * 2] = a; red[t * 2 + 1] = aa;
    }
    for (int m = 0; m < 3; ++m) {
        const __bf16* src = (m == 0) ? wqt : (m == 1) ? wkt : wvt;
        for (int i = 0; i < 2; ++i) {
            int e = i * 256 + t, row = e >> 3, ch = e & 7;
            *(bf8*)&W[m][row][ch * 8] = *(const bf8*)(src + row * 64 + ch * 8);
        }
    }
    __syncthreads();
    if (t < 8) {
        float a = 0.f, aa = 0.f;
        for (int c = 0; c < 8; ++c) {
            a  += red[(c * 8 + t) * 2];
            aa += red[(c * 8 + t) * 2 + 1];
        }
        float mean = a * (1.f / 32768.f);
        float var = aa * (1.f / 32768.f) - mean * mean;
        sstat[t * 2 + 0] = mean;
        sstat[t * 2 + 1] = rsqrtf(var + 1e-3f);
    }
    __syncthreads();
    {
        int c4 = (t & 15) * 4, grp = c4 >> 3;
        float mean = sstat[grp * 2], rstd = sstat[grp * 2 + 1];
        float g0 = gamma[c4] * rstd, g1 = gamma[c4 + 1] * rstd,
              g2 = gamma[c4 + 2] * rstd, g3 = gamma[c4 + 3] * rstd;
        float b0 = beta[c4], b1 = beta[c4 + 1], b2 = beta[c4 + 2], b3 = beta[c4 + 3];
        const float4* xb = (const float4*)(x + rowbase * 64);
        for (int i = 0; i < 4; ++i) {
            int row = (t >> 4) + i * 16;
            float4 v = xb[row * 16 + (t & 15)];
            bf4 hv;
            hv[0] = (__bf16)((v.x - mean) * g0 + b0);
            hv[1] = (__bf16)((v.y - mean) * g1 + b1);
            hv[2] = (__bf16)((v.z - mean) * g2 + b2);
            hv[3] = (__bf16)((v.w - mean) * g3 + b3);
            *(bf4*)&Hl[row][c4] = hv;
        }
    }
    __syncthreads();
    int lane = t & 63, wave = t >> 6, quad = lane >> 4, l15 = lane & 15;
    bf8 a0 = *(const bf8*)&Hl[wave * 16 + l15][quad * 8];
    bf8 a1 = *(const bf8*)&Hl[wave * 16 + l15][32 + quad * 8];
    for (int m = 0; m < 3; ++m) {
        const float* bias = (m == 0) ? bq : (m == 1) ? bk : bv;
        float sc = (m == 0) ? 0.125f * LOG2E : 1.0f;
        for (int tt = 0; tt < 4; ++tt) {
            int col = l15 + 16 * tt;
            bf8 b0 = *(const bf8*)&W[m][col][quad * 8];
            bf8 b1 = *(const bf8*)&W[m][col][32 + quad * 8];
            f4 acc = {0.f, 0.f, 0.f, 0.f};
            acc = mfma16(a0, b0, acc);
            acc = mfma16(a1, b1, acc);
            float bb = bias[col];
            if (m == 2) {
                for (int r = 0; r < 4; ++r)
                    Vst[col][wave * 16 + quad * 4 + r] = (_Float16)(acc[r] + bb);
            } else {
                __bf16* dst = (m == 0) ? q : k;
                for (int r = 0; r < 4; ++r) {
                    float val = (acc[r] + bb) * sc;
                    dst[(rowbase + wave * 16 + quad * 4 + r) * 64 + col] = (__bf16)val;
                }
            }
        }
    }
    __syncthreads();
    {   // fragment-layout V^T writeout: vt[ktile*1024 + p*512 + (q4*16+dl)*8 + u*4 + r]
        int d = t >> 2, seg = t & 3;
        int ktile = (tokbase >> 4) + seg;
        int p = d >> 5, u = (d >> 4) & 1, dl = d & 15;
        _Float16* base = vT + (size_t)b * 262144 + (size_t)ktile * 1024 + p * 512 + u * 4;
        for (int q4 = 0; q4 < 4; ++q4) {
            h4 c = *(const h4*)&Vst[d][seg * 16 + q4 * 4];
            *(h4*)(base + (q4 * 16 + dl) * 8) = c;
        }
    }
}

// ---------------- fused attention + output projection + residual -------------------------
// grid 512 = qt*8 + b (batch -> XCD L2 locality); block 256 = 4 waves.
// Wave w owns key chunk [w*1024, +1024): 64 iters x 16 keys, all 64 q.
// V loads are 2 x b128 per tile (fragment layout) -> 4 L2 requests/iter (the b128 floor).
__global__ __launch_bounds__(256, 2) void attn_final(const __bf16* __restrict__ q,
                                                     const __bf16* __restrict__ k,
                                                     const _Float16* __restrict__ vt,
                                                     const __bf16* __restrict__ wpt,
                                                     const float* __restrict__ bp,
                                                     const float* __restrict__ x,
                                                     const float* __restrict__ gpart,
                                                     const float* __restrict__ gamma,
                                                     const float* __restrict__ beta,
                                                     float* __restrict__ out) {
    __shared__ _Float16 Om[2][64][72];
    __shared__ float sS[2][64];
    __shared__ __bf16 Wl[64][72];
    __shared__ __bf16 Ol[64][72];
    __shared__ float red[128];
    __shared__ float sstat[16], sg[64], sb[64];

    int bid = blockIdx.x;
    int qt = bid >> 3, b = bid & 7;
    int t = threadIdx.x, lane = t & 63, w = t >> 6, quad = lane >> 4, l15 = lane & 15;

    for (int i = 0; i < 2; ++i) {
        int e = i * 256 + t, row = e >> 3, ch = e & 7;
        *(bf8*)&Wl[row][ch * 8] = *(const bf8*)(wpt + row * 64 + ch * 8);
    }
    if (t < 64) { sg[t] = gamma[t]; sb[t] = beta[t]; }
    if (t < 64) {
        int gi = t & 7, c = t >> 3;
        const float2* gp = (const float2*)gpart + (size_t)b * 512 + gi;
        float a = 0.f, aa = 0.f;
        for (int p = c * 8; p < c * 8 + 8; ++p) {
            float2 v = gp[(size_t)p * 8];
            a += v.x; aa += v.y;
        }
        red[t * 2] = a; red[t * 2 + 1] = aa;
    }

    const __bf16* qbase = q + ((size_t)b * NTOK + qt * 64) * 64;
    bf8 aq[4][2];
    for (int s = 0; s < 4; ++s) {
        const __bf16* r = qbase + (s * 16 + l15) * 64;
        aq[s][0] = *(const bf8*)(r + quad * 8);
        aq[s][1] = *(const bf8*)(r + 32 + quad * 8);
    }
    // strip base pointers; advance 16 keys (=1024 bf16 K / 1024 vt-elem) per iter
    const __bf16* kr = k + ((size_t)b * NTOK + w * 1024 + l15) * 64;
    const _Float16* vr = vt + (size_t)b * 262144 + (size_t)(w * 64) * 1024 + lane * 8;

    f4 acc[4][4] = {};
    float li[4] = {0.f, 0.f, 0.f, 0.f};

    // preload iter 0
    bf8 kf0 = *(const bf8*)(kr + quad * 8);
    bf8 kf1 = *(const bf8*)(kr + 32 + quad * 8);
    h8 va = *(const h8*)(vr);         // td0 (u=0) + td1 (u=1)
    h8 vb = *(const h8*)(vr + 512);   // td2 + td3

    #pragma unroll 1
    for (int it = 0; it < 64; ++it) {
        int nx = (it + 1) & 63;   // wraps on last iter: harmless L2-hit re-read
        const __bf16* krn = kr + (size_t)nx * 1024;
        const _Float16* vrn = vr + (size_t)nx * 1024;
        bf8 nk0 = *(const bf8*)(krn + quad * 8);
        bf8 nk1 = *(const bf8*)(krn + 32 + quad * 8);
        h8 nva = *(const h8*)(vrn);
        h8 nvb = *(const h8*)(vrn + 512);

        h4 vf0 = {va[0], va[1], va[2], va[3]};
        h4 vf1 = {va[4], va[5], va[6], va[7]};
        h4 vf2 = {vb[0], vb[1], vb[2], vb[3]};
        h4 vf3 = {vb[4], vb[5], vb[6], vb[7]};

        for (int s = 0; s < 4; ++s) {
            f4 St = {0.f, 0.f, 0.f, 0.f};
            St = mfma16(kf0, aq[s][0], St);
            St = mfma16(kf1, aq[s][1], St);
            h4 pf;
            for (int r = 0; r < 4; ++r) {
                float pv = __builtin_amdgcn_exp2f(St[r]);
                li[s] += pv;
                pf[r] = (_Float16)pv;
            }
            acc[s][0] = mfma16h(vf0, pf, acc[s][0]);
            acc[s][1] = mfma16h(vf1, pf, acc[s][1]);
            acc[s][2] = mfma16h(vf2, pf, acc[s][2]);
            acc[s][3] = mfma16h(vf3, pf, acc[s][3]);
        }
        kf0 = nk0; kf1 = nk1;
        va = nva; vb = nvb;
    }

    // quad-reduce li
    for (int s = 0; s < 4; ++s) {
        li[s] += __shfl_xor(li[s], 16);
        li[s] += __shfl_xor(li[s], 32);
    }

    // 3-phase pairwise merge (18.9 KB of merge LDS)
    if (w >= 2) {   // phase 1: waves 2,3 deposit
        for (int s = 0; s < 4; ++s) {
            for (int td = 0; td < 4; ++td) {
                h4 o4;
                for (int r = 0; r < 4; ++r) o4[r] = (_Float16)acc[s][td][r];
                *(h4*)&Om[w - 2][s * 16 + l15][td * 16 + quad * 4] = o4;
            }
            if (quad == 0) sS[w - 2][s * 16 + l15] = li[s];
        }
    }
    __syncthreads();
    if (t < 8) {    // GN stats finalize (red visible now)
        float a = 0.f, aa = 0.f;
        for (int c = 0; c < 8; ++c) {
            a  += red[(c * 8 + t) * 2];
            aa += red[(c * 8 + t) * 2 + 1];
        }
        float mean = a * (1.f / 32768.f);
        float var = aa * (1.f / 32768.f) - mean * mean;
        sstat[t * 2 + 0] = mean;
        sstat[t * 2 + 1] = rsqrtf(var + 1e-3f);
    }
    if (w < 2) {    // waves 0,1 absorb
        for (int s = 0; s < 4; ++s) {
            for (int td = 0; td < 4; ++td) {
                h4 o4 = *(const h4*)&Om[w][s * 16 + l15][td * 16 + quad * 4];
                for (int r = 0; r < 4; ++r) acc[s][td][r] += (float)o4[r];
            }
            li[s] += sS[w][s * 16 + l15];
        }
    }
    __syncthreads();
    if (w < 2) {    // phase 2: deposit pair-sums
        for (int s = 0; s < 4; ++s) {
            for (int td = 0; td < 4; ++td) {
                h4 o4;
                for (int r = 0; r < 4; ++r) o4[r] = (_Float16)acc[s][td][r];
                *(h4*)&Om[w][s * 16 + l15][td * 16 + quad * 4] = o4;
            }
            if (quad == 0) sS[w][s * 16 + l15] = li[s];
        }
    }
    __syncthreads();
    {   // phase 3: combine + normalize into Ol (bf16)
        int qq = t >> 2, ds = (t & 3) * 16;
        float inv = 1.f / (sS[0][qq] + sS[1][qq]);
        h8 a0 = *(const h8*)&Om[0][qq][ds];
        h8 b0 = *(const h8*)&Om[0][qq][ds + 8];
        h8 a1 = *(const h8*)&Om[1][qq][ds];
        h8 b1 = *(const h8*)&Om[1][qq][ds + 8];
        bf8 olo, ohi;
        for (int j = 0; j < 8; ++j) {
            olo[j] = (__bf16)(((float)a0[j] + (float)a1[j]) * inv);
            ohi[j] = (__bf16)(((float)b0[j] + (float)b1[j]) * inv);
        }
        *(bf8*)&Ol[qq][ds] = olo;
        *(bf8*)&Ol[qq][ds + 8] = ohi;
    }
    __syncthreads();
    // epilogue: out = Ol @ wp^T + bp + GN(x)
    size_t rowbase = ((size_t)b * NTOK + qt * 64) + w * 16;
    bf8 a0 = *(const bf8*)&Ol[w * 16 + l15][quad * 8];
    bf8 a1 = *(const bf8*)&Ol[w * 16 + l15][32 + quad * 8];
    for (int tt = 0; tt < 4; ++tt) {
        int col = l15 + 16 * tt;
        bf8 b0 = *(const bf8*)&Wl[col][quad * 8];
        bf8 b1 = *(const bf8*)&Wl[col][32 + quad * 8];
        f4 pacc = {0.f, 0.f, 0.f, 0.f};
        pacc = mfma16(a0, b0, pacc);
        pacc = mfma16(a1, b1, pacc);
        int grp = col >> 3;
        float mean = sstat[grp * 2], gs = sg[col] * sstat[grp * 2 + 1], bs = sb[col];
        float bias = bp[col];
        for (int r = 0; r < 4; ++r) {
            size_t gi = (rowbase + quad * 4 + r) * 64 + col;
            float h = (x[gi] - mean) * gs + bs;
            out[gi] = pacc[r] + bias + h;
        }
    }
}

extern "C" void kernel_launch(void* const* d_in, const int* in_sizes, int n_in,
                              void* d_out, int out_size, void* d_ws, size_t ws_size,
                              hipStream_t stream) {
    const float* x     = (const float*)d_in[0];
    const float* gamma = (const float*)d_in[1];
    const float* beta  = (const float*)d_in[2];
    const float* wq    = (const float*)d_in[3];
    const float* bq    = (const float*)d_in[4];
    const float* wk    = (const float*)d_in[5];
    const float* bk    = (const float*)d_in[6];
    const float* wv    = (const float*)d_in[7];
    const float* bv    = (const float*)d_in[8];
    const float* wp    = (const float*)d_in[9];
    const float* bp    = (const float*)d_in[10];
    float* out = (float*)d_out;

    char* ws = (char*)d_ws;
    const size_t MB = 1024 * 1024;
    __bf16*   qb   = (__bf16*)(ws);                 // 4 MB
    __bf16*   kb   = (__bf16*)(ws + 4 * MB);        // 4 MB
    _Float16* vtb  = (_Float16*)(ws + 8 * MB);      // 4 MB (fragment-layout V fp16)
    __bf16*   wqt  = (__bf16*)(ws + 12 * MB);
    __bf16*   wkt  = (__bf16*)(ws + 12 * MB + 8192);
    __bf16*   wvt  = (__bf16*)(ws + 12 * MB + 16384);
    __bf16*   wpt  = (__bf16*)(ws + 12 * MB + 24576);
    float*    gpart = (float*)(ws + 12 * MB + 32768);   // 32 KB

    pre_kernel<<<516, 256, 0, stream>>>(wq, wk, wv, wp, x, wqt, wkt, wvt, wpt, gpart);
    qkv_gn<<<512, 256, 0, stream>>>(x, gpart, gamma, beta, wqt, wkt, wvt, bq, bk, bv, qb, kb, vtb);
    attn_final<<<512, 256, 0, stream>>>(qb, kb, vtb, wpt, bp, x, gpart, gamma, beta, out);
}

// Round 13
// 133.298 us; speedup vs baseline: 2.1984x; 1.0234x over previous
//
#include <hip/hip_runtime.h>

#define NTOK 4096
#define CH 64
#define LOG2E 1.4426950408889634f

typedef __bf16 bf8 __attribute__((ext_vector_type(8)));
typedef __bf16 bf4 __attribute__((ext_vector_type(4)));
typedef _Float16 h8 __attribute__((ext_vector_type(8)));
typedef _Float16 h4 __attribute__((ext_vector_type(4)));
typedef float f4 __attribute__((ext_vector_type(4)));

__device__ __forceinline__ f4 mfma16(bf8 a, bf8 b, f4 c) {
    return __builtin_amdgcn_mfma_f32_16x16x32_bf16(a, b, c, 0, 0, 0);
}
__device__ __forceinline__ f4 mfma32h(h8 a, h8 b, f4 c) {
    return __builtin_amdgcn_mfma_f32_16x16x32_f16(a, b, c, 0, 0, 0);
}

// ---------------- fused pre-pass: blocks 0..3 = weight transpose; 4..515 = GN partials ----
__global__ __launch_bounds__(256) void pre_kernel(const float* __restrict__ wq,
                                                  const float* __restrict__ wk,
                                                  const float* __restrict__ wv,
                                                  const float* __restrict__ wp,
                                                  const float* __restrict__ x,
                                                  __bf16* __restrict__ wqt,
                                                  __bf16* __restrict__ wkt,
                                                  __bf16* __restrict__ wvt,
                                                  __bf16* __restrict__ wpt,
                                                  float* __restrict__ gpart) {
    int t = threadIdx.x;
    if (blockIdx.x < 4) {   // weight transpose + bf16 convert
        int m = blockIdx.x;
        const float* src = (m == 0) ? wq : (m == 1) ? wk : (m == 2) ? wv : wp;
        __bf16* dst      = (m == 0) ? wqt : (m == 1) ? wkt : (m == 2) ? wvt : wpt;
        __shared__ float s[64][65];
        for (int i = 0; i < 16; ++i) {
            int e = i * 256 + t;
            s[e >> 6][e & 63] = src[e];
        }
        __syncthreads();
        int o = t >> 2, seg = t & 3;
        for (int j = 0; j < 16; ++j) {
            int in = seg * 16 + j;
            dst[o * 64 + in] = (__bf16)s[in][o];
        }
        return;
    }
    // GN partial sums: 512 blocks = 8b x 64 slabs of 64 rows
    int bid = blockIdx.x - 4;
    int b = bid >> 6, slab = bid & 63;
    const float4* xb = (const float4*)(x + (size_t)(b * NTOK + slab * 64) * CH);
    float s = 0.f, ss = 0.f;
    for (int i = 0; i < 4; ++i) {
        int row = (t >> 4) + i * 16;
        float4 v = xb[row * 16 + (t & 15)];
        s  += v.x + v.y + v.z + v.w;
        ss += v.x * v.x + v.y * v.y + v.z * v.z + v.w * v.w;
    }
    __shared__ float ls[256], lss[256];
    ls[t] = s; lss[t] = ss;
    __syncthreads();
    if (t < 8) {
        float a = 0.f, aa = 0.f;
        for (int p = 0; p < 16; ++p) {
            a  += ls[p * 16 + 2 * t]  + ls[p * 16 + 2 * t + 1];
            aa += lss[p * 16 + 2 * t] + lss[p * 16 + 2 * t + 1];
        }
        gpart[((b * 64 + slab) * 8 + t) * 2 + 0] = a;
        gpart[((b * 64 + slab) * 8 + t) * 2 + 1] = aa;
    }
}

// ---------------- fused GN + QKV projection (grid 512, 64 rows/block) --------------------
// V written fp16 in slot-permuted K=32 fragment layout:
//   vt[((b*128 + kt32)*4 + td)*64 + lane] (h8): lane=(quad,l15) holds
//   V^T[d=td*16+l15][slot quad*8+j], slot j<4 -> key quad*4+j ; j>=4 -> 16+quad*4+(j-4)
__global__ __launch_bounds__(256) void qkv_gn(const float* __restrict__ x,
                                              const float* __restrict__ gpart,
                                              const float* __restrict__ gamma,
                                              const float* __restrict__ beta,
                                              const __bf16* __restrict__ wqt,
                                              const __bf16* __restrict__ wkt,
                                              const __bf16* __restrict__ wvt,
                                              const float* __restrict__ bq,
                                              const float* __restrict__ bk,
                                              const float* __restrict__ bv,
                                              __bf16* __restrict__ q,
                                              __bf16* __restrict__ k,
                                              _Float16* __restrict__ vT) {
    __shared__ __bf16 W[3][64][72];
    __shared__ __bf16 Hl[64][72];
    __shared__ _Float16 Vst[64][68];
    __shared__ float red[128];
    __shared__ float sstat[16];
    int t = threadIdx.x;
    size_t rowbase = (size_t)blockIdx.x * 64;
    int b = (int)(rowbase >> 12), tokbase = (int)(rowbase & 4095);
    if (t < 64) {
        int gi = t & 7, c = t >> 3;
        const float2* gp = (const float2*)gpart + (size_t)b * 512 + gi;
        float a = 0.f, aa = 0.f;
        for (int p = c * 8; p < c * 8 + 8; ++p) {
            float2 v = gp[(size_t)p * 8];
            a += v.x; aa += v.y;
        }
        red[t * 2] = a; red[t * 2 + 1] = aa;
    }
    for (int m = 0; m < 3; ++m) {
        const __bf16* src = (m == 0) ? wqt : (m == 1) ? wkt : wvt;
        for (int i = 0; i < 2; ++i) {
            int e = i * 256 + t, row = e >> 3, ch = e & 7;
            *(bf8*)&W[m][row][ch * 8] = *(const bf8*)(src + row * 64 + ch * 8);
        }
    }
    __syncthreads();
    if (t < 8) {
        float a = 0.f, aa = 0.f;
        for (int c = 0; c < 8; ++c) {
            a  += red[(c * 8 + t) * 2];
            aa += red[(c * 8 + t) * 2 + 1];
        }
        float mean = a * (1.f / 32768.f);
        float var = aa * (1.f / 32768.f) - mean * mean;
        sstat[t * 2 + 0] = mean;
        sstat[t * 2 + 1] = rsqrtf(var + 1e-3f);
    }
    __syncthreads();
    {
        int c4 = (t & 15) * 4, grp = c4 >> 3;
        float mean = sstat[grp * 2], rstd = sstat[grp * 2 + 1];
        float g0 = gamma[c4] * rstd, g1 = gamma[c4 + 1] * rstd,
              g2 = gamma[c4 + 2] * rstd, g3 = gamma[c4 + 3] * rstd;
        float b0 = beta[c4], b1 = beta[c4 + 1], b2 = beta[c4 + 2], b3 = beta[c4 + 3];
        const float4* xb = (const float4*)(x + rowbase * 64);
        for (int i = 0; i < 4; ++i) {
            int row = (t >> 4) + i * 16;
            float4 v = xb[row * 16 + (t & 15)];
            bf4 hv;
            hv[0] = (__bf16)((v.x - mean) * g0 + b0);
            hv[1] = (__bf16)((v.y - mean) * g1 + b1);
            hv[2] = (__bf16)((v.z - mean) * g2 + b2);
            hv[3] = (__bf16)((v.w - mean) * g3 + b3);
            *(bf4*)&Hl[row][c4] = hv;
        }
    }
    __syncthreads();
    int lane = t & 63, wave = t >> 6, quad = lane >> 4, l15 = lane & 15;
    bf8 a0 = *(const bf8*)&Hl[wave * 16 + l15][quad * 8];
    bf8 a1 = *(const bf8*)&Hl[wave * 16 + l15][32 + quad * 8];
    for (int m = 0; m < 3; ++m) {
        const float* bias = (m == 0) ? bq : (m == 1) ? bk : bv;
        float sc = (m == 0) ? 0.125f * LOG2E : 1.0f;
        for (int tt = 0; tt < 4; ++tt) {
            int col = l15 + 16 * tt;
            bf8 b0 = *(const bf8*)&W[m][col][quad * 8];
            bf8 b1 = *(const bf8*)&W[m][col][32 + quad * 8];
            f4 acc = {0.f, 0.f, 0.f, 0.f};
            acc = mfma16(a0, b0, acc);
            acc = mfma16(a1, b1, acc);
            float bb = bias[col];
            if (m == 2) {
                for (int r = 0; r < 4; ++r)
                    Vst[col][wave * 16 + quad * 4 + r] = (_Float16)(acc[r] + bb);
            } else {
                __bf16* dst = (m == 0) ? q : k;
                for (int r = 0; r < 4; ++r) {
                    float val = (acc[r] + bb) * sc;
                    dst[(rowbase + wave * 16 + quad * 4 + r) * 64 + col] = (__bf16)val;
                }
            }
        }
    }
    __syncthreads();
    {   // slot-permuted V writeout (two 32-key tiles per block)
        int d = wave * 16 + l15;
        for (int kb = 0; kb < 2; ++kb) {
            h4 lo = *(const h4*)&Vst[d][kb * 32 + quad * 4];
            h4 hi = *(const h4*)&Vst[d][kb * 32 + 16 + quad * 4];
            h8 o;
            o[0] = lo[0]; o[1] = lo[1]; o[2] = lo[2]; o[3] = lo[3];
            o[4] = hi[0]; o[5] = hi[1]; o[6] = hi[2]; o[7] = hi[3];
            _Float16* dst = vT + ((((size_t)b * 128 + (tokbase >> 5) + kb) * 4 + wave) * 64
                                  + lane) * 8;
            *(h8*)dst = o;
        }
    }
}

// ---------------- fused attention + output projection + residual -------------------------
// grid 512 = qt*8 + b; block 256 = 4 waves; wave owns 1024 keys = 32 iters x 32 keys.
// QK^T: 2 subtiles of 16 keys (bf16 K=32 MFMA); PV: K=32 f16 MFMA with slot-permuted V.
// Per 32 keys: 8 b128 loads (byte floor), 16 QK + 16 PV MFMA (was 16+32).
__global__ __launch_bounds__(256, 2) void attn_final(const __bf16* __restrict__ q,
                                                     const __bf16* __restrict__ k,
                                                     const _Float16* __restrict__ vt,
                                                     const __bf16* __restrict__ wpt,
                                                     const float* __restrict__ bp,
                                                     const float* __restrict__ x,
                                                     const float* __restrict__ gpart,
                                                     const float* __restrict__ gamma,
                                                     const float* __restrict__ beta,
                                                     float* __restrict__ out) {
    __shared__ _Float16 Om[2][64][72];
    __shared__ float sS[2][64];
    __shared__ __bf16 Wl[64][72];
    __shared__ __bf16 Ol[64][72];
    __shared__ float red[128];
    __shared__ float sstat[16], sg[64], sb[64];

    int bid = blockIdx.x;
    int qt = bid >> 3, b = bid & 7;
    int t = threadIdx.x, lane = t & 63, w = t >> 6, quad = lane >> 4, l15 = lane & 15;

    for (int i = 0; i < 2; ++i) {
        int e = i * 256 + t, row = e >> 3, ch = e & 7;
        *(bf8*)&Wl[row][ch * 8] = *(const bf8*)(wpt + row * 64 + ch * 8);
    }
    if (t < 64) { sg[t] = gamma[t]; sb[t] = beta[t]; }
    if (t < 64) {
        int gi = t & 7, c = t >> 3;
        const float2* gp = (const float2*)gpart + (size_t)b * 512 + gi;
        float a = 0.f, aa = 0.f;
        for (int p = c * 8; p < c * 8 + 8; ++p) {
            float2 v = gp[(size_t)p * 8];
            a += v.x; aa += v.y;
        }
        red[t * 2] = a; red[t * 2 + 1] = aa;
    }

    const __bf16* qbase = q + ((size_t)b * NTOK + qt * 64) * 64;
    bf8 aq[4][2];
    for (int s = 0; s < 4; ++s) {
        const __bf16* r = qbase + (s * 16 + l15) * 64;
        aq[s][0] = *(const bf8*)(r + quad * 8);
        aq[s][1] = *(const bf8*)(r + 32 + quad * 8);
    }
    const __bf16* kbase   = k  + ((size_t)b * NTOK + w * 1024) * 64;
    const _Float16* vbase = vt + (size_t)b * 262144 + (size_t)(w * 32) * 2048 + lane * 8;

    f4 acc[4][4] = {};
    float li[4] = {0.f, 0.f, 0.f, 0.f};

    for (int it = 0; it < 32; ++it) {
        const __bf16* kr0 = kbase + (size_t)(it * 32 + l15) * 64;
        const __bf16* kr1 = kr0 + 16 * 64;
        bf8 kf00 = *(const bf8*)(kr0 + quad * 8);
        bf8 kf01 = *(const bf8*)(kr0 + 32 + quad * 8);
        bf8 kf10 = *(const bf8*)(kr1 + quad * 8);
        bf8 kf11 = *(const bf8*)(kr1 + 32 + quad * 8);
        const _Float16* vr = vbase + (size_t)it * 2048;
        h8 vf0 = *(const h8*)(vr);
        h8 vf1 = *(const h8*)(vr + 512);
        h8 vf2 = *(const h8*)(vr + 1024);
        h8 vf3 = *(const h8*)(vr + 1536);

        for (int s = 0; s < 4; ++s) {
            f4 St0 = {0.f, 0.f, 0.f, 0.f};
            f4 St1 = {0.f, 0.f, 0.f, 0.f};
            St0 = mfma16(kf00, aq[s][0], St0);
            St0 = mfma16(kf01, aq[s][1], St0);
            St1 = mfma16(kf10, aq[s][0], St1);
            St1 = mfma16(kf11, aq[s][1], St1);
            h8 pf;
            float rs = 0.f;
            for (int r = 0; r < 4; ++r) {
                float p0 = __builtin_amdgcn_exp2f(St0[r]);
                float p1 = __builtin_amdgcn_exp2f(St1[r]);
                rs += p0 + p1;
                pf[r]     = (_Float16)p0;
                pf[4 + r] = (_Float16)p1;
            }
            li[s] += rs;
            acc[s][0] = mfma32h(vf0, pf, acc[s][0]);
            acc[s][1] = mfma32h(vf1, pf, acc[s][1]);
            acc[s][2] = mfma32h(vf2, pf, acc[s][2]);
            acc[s][3] = mfma32h(vf3, pf, acc[s][3]);
        }
    }

    // quad-reduce li
    for (int s = 0; s < 4; ++s) {
        li[s] += __shfl_xor(li[s], 16);
        li[s] += __shfl_xor(li[s], 32);
    }

    // 3-phase pairwise merge (18.9 KB of merge LDS)
    if (w >= 2) {   // phase 1: waves 2,3 deposit
        for (int s = 0; s < 4; ++s) {
            for (int td = 0; td < 4; ++td) {
                h4 o4;
                for (int r = 0; r < 4; ++r) o4[r] = (_Float16)acc[s][td][r];
                *(h4*)&Om[w - 2][s * 16 + l15][td * 16 + quad * 4] = o4;
            }
            if (quad == 0) sS[w - 2][s * 16 + l15] = li[s];
        }
    }
    __syncthreads();
    if (t < 8) {    // GN stats finalize (red visible now)
        float a = 0.f, aa = 0.f;
        for (int c = 0; c < 8; ++c) {
            a  += red[(c * 8 + t) * 2];
            aa += red[(c * 8 + t) * 2 + 1];
        }
        float mean = a * (1.f / 32768.f);
        float var = aa * (1.f / 32768.f) - mean * mean;
        sstat[t * 2 + 0] = mean;
        sstat[t * 2 + 1] = rsqrtf(var + 1e-3f);
    }
    if (w < 2) {    // waves 0,1 absorb
        for (int s = 0; s < 4; ++s) {
            for (int td = 0; td < 4; ++td) {
                h4 o4 = *(const h4*)&Om[w][s * 16 + l15][td * 16 + quad * 4];
                for (int r = 0; r < 4; ++r) acc[s][td][r] += (float)o4[r];
            }
            li[s] += sS[w][s * 16 + l15];
        }
    }
    __syncthreads();
    if (w < 2) {    // phase 2: deposit pair-sums
        for (int s = 0; s < 4; ++s) {
            for (int td = 0; td < 4; ++td) {
                h4 o4;
                for (int r = 0; r < 4; ++r) o4[r] = (_Float16)acc[s][td][r];
                *(h4*)&Om[w][s * 16 + l15][td * 16 + quad * 4] = o4;
            }
            if (quad == 0) sS[w][s * 16 + l15] = li[s];
        }
    }
    __syncthreads();
    {   // phase 3: combine + normalize into Ol (bf16)
        int qq = t >> 2, ds = (t & 3) * 16;
        float inv = 1.f / (sS[0][qq] + sS[1][qq]);
        h8 a0 = *(const h8*)&Om[0][qq][ds];
        h8 b0 = *(const h8*)&Om[0][qq][ds + 8];
        h8 a1 = *(const h8*)&Om[1][qq][ds];
        h8 b1 = *(const h8*)&Om[1][qq][ds + 8];
        bf8 olo, ohi;
        for (int j = 0; j < 8; ++j) {
            olo[j] = (__bf16)(((float)a0[j] + (float)a1[j]) * inv);
            ohi[j] = (__bf16)(((float)b0[j] + (float)b1[j]) * inv);
        }
        *(bf8*)&Ol[qq][ds] = olo;
        *(bf8*)&Ol[qq][ds + 8] = ohi;
    }
    __syncthreads();
    // epilogue: out = Ol @ wp^T + bp + GN(x)
    size_t rowbase = ((size_t)b * NTOK + qt * 64) + w * 16;
    bf8 a0 = *(const bf8*)&Ol[w * 16 + l15][quad * 8];
    bf8 a1 = *(const bf8*)&Ol[w * 16 + l15][32 + quad * 8];
    for (int tt = 0; tt < 4; ++tt) {
        int col = l15 + 16 * tt;
        bf8 b0 = *(const bf8*)&Wl[col][quad * 8];
        bf8 b1 = *(const bf8*)&Wl[col][32 + quad * 8];
        f4 pacc = {0.f, 0.f, 0.f, 0.f};
        pacc = mfma16(a0, b0, pacc);
        pacc = mfma16(a1, b1, pacc);
        int grp = col >> 3;
        float mean = sstat[grp * 2], gs = sg[col] * sstat[grp * 2 + 1], bs = sb[col];
        float bias = bp[col];
        for (int r = 0; r < 4; ++r) {
            size_t gi = (rowbase + quad * 4 + r) * 64 + col;
            float h = (x[gi] - mean) * gs + bs;
            out[gi] = pacc[r] + bias + h;
        }
    }
}

extern "C" void kernel_launch(void* const* d_in, const int* in_sizes, int n_in,
                              void* d_out, int out_size, void* d_ws, size_t ws_size,
                              hipStream_t stream) {
    const float* x     = (const float*)d_in[0];
    const float* gamma = (const float*)d_in[1];
    const float* beta  = (const float*)d_in[2];
    const float* wq    = (const float*)d_in[3];
    const float* bq    = (const float*)d_in[4];
    const float* wk    = (const float*)d_in[5];
    const float* bk    = (const float*)d_in[6];
    const float* wv    = (const float*)d_in[7];
    const float* bv    = (const float*)d_in[8];
    const float* wp    = (const float*)d_in[9];
    const float* bp    = (const float*)d_in[10];
    float* out = (float*)d_out;

    char* ws = (char*)d_ws;
    const size_t MB = 1024 * 1024;
    __bf16*   qb   = (__bf16*)(ws);                 // 4 MB
    __bf16*   kb   = (__bf16*)(ws + 4 * MB);        // 4 MB
    _Float16* vtb  = (_Float16*)(ws + 8 * MB);      // 4 MB (slot-permuted V fp16)
    __bf16*   wqt  = (__bf16*)(ws + 12 * MB);
    __bf16*   wkt  = (__bf16*)(ws + 12 * MB + 8192);
    __bf16*   wvt  = (__bf16*)(ws + 12 * MB + 16384);
    __bf16*   wpt  = (__bf16*)(ws + 12 * MB + 24576);
    float*    gpart = (float*)(ws + 12 * MB + 32768);   // 32 KB

    pre_kernel<<<516, 256, 0, stream>>>(wq, wk, wv, wp, x, wqt, wkt, wvt, wpt, gpart);
    qkv_gn<<<512, 256, 0, stream>>>(x, gpart, gamma, beta, wqt, wkt, wvt, bq, bk, bv, qb, kb, vtb);
    attn_final<<<512, 256, 0, stream>>>(qb, kb, vtb, wpt, bp, x, gpart, gamma, beta, out);
}